// Round 1
// baseline (2207.479 us; speedup 1.0000x reference)
//
#include <hip/hip_runtime.h>
#include <math.h>

#define NNODES 50000
#define NEDGES 800000
#define BN_EPS 1e-5f

// ---------------- dense matmul: H[N,F] = X[N,K] @ W[K,F] ----------------
__global__ void matmul16(const float* __restrict__ X, const float* __restrict__ W,
                         float* __restrict__ Hout, int N, int K, int F) {
    __shared__ float sX[16][17];
    __shared__ float sW[16][17];
    int row = blockIdx.x * 16 + threadIdx.y;
    int col = blockIdx.y * 16 + threadIdx.x;
    float acc = 0.f;
    for (int k0 = 0; k0 < K; k0 += 16) {
        sX[threadIdx.y][threadIdx.x] = (row < N) ? X[row * K + k0 + threadIdx.x] : 0.f;
        sW[threadIdx.y][threadIdx.x] = W[(k0 + threadIdx.y) * F + col];
        __syncthreads();
#pragma unroll
        for (int k = 0; k < 16; ++k) acc += sX[threadIdx.y][k] * sW[k][threadIdx.x];
        __syncthreads();
    }
    if (row < N) Hout[row * F + col] = acc;
}

// ---------------- per-node attention scores ----------------
// es[n*H+h] = sum_d h[n,h,d]*a_src[h,d]; ed likewise
template <int HH, int DD>
__global__ void attn_scores(const float* __restrict__ Hb, const float* __restrict__ asrc,
                            const float* __restrict__ adst, float* __restrict__ es,
                            float* __restrict__ ed) {
    int idx = blockIdx.x * blockDim.x + threadIdx.x;
    if (idx >= NNODES * HH) return;
    int n = idx / HH, h = idx % HH;
    const float* hp = Hb + (n * HH + h) * DD;
    float s = 0.f, t = 0.f;
#pragma unroll
    for (int d = 0; d < DD; ++d) {
        float v = hp[d];
        s += v * asrc[h * DD + d];
        t += v * adst[h * DD + d];
    }
    es[idx] = s;
    ed[idx] = t;
}

// ---------------- edge pass 1: ex = exp(leaky(es[s]+ed[d])); den[d] += ex ----------------
// (segment-max skipped: it cancels exactly in the softmax ratio; alpha is O(1) here)
template <int HH>
__global__ void edge_ex(const int* __restrict__ src, const int* __restrict__ dst,
                        const float* __restrict__ es, const float* __restrict__ ed,
                        float* __restrict__ exw, float* __restrict__ den) {
    const int total = (NEDGES + NNODES) * HH;
    for (int idx = blockIdx.x * blockDim.x + threadIdx.x; idx < total;
         idx += gridDim.x * blockDim.x) {
        int e = idx / HH, h = idx - (idx / HH) * HH;
        int s, d;
        if (e < NEDGES) { s = src[e]; d = dst[e]; } else { s = e - NEDGES; d = s; }
        float a = es[s * HH + h] + ed[d * HH + h];
        a = a > 0.f ? a : 0.2f * a;
        float ex = expf(a);
        exw[idx] = ex;
        atomicAdd(&den[d * HH + h], ex);
    }
}

// ---------------- edge pass 2: out[d,f] += (ex/den[d]) * h[s,f] ----------------
template <int HH, int DD>
__global__ void edge_agg(const int* __restrict__ src, const int* __restrict__ dst,
                         const float* __restrict__ Hb, const float* __restrict__ exw,
                         const float* __restrict__ den, float* __restrict__ out) {
    const int F = HH * DD;
    const long long total = (long long)(NEDGES + NNODES) * F;
    for (long long idx = blockIdx.x * (long long)blockDim.x + threadIdx.x; idx < total;
         idx += (long long)gridDim.x * blockDim.x) {
        int e = (int)(idx / F);
        int f = (int)(idx - (long long)e * F);
        int h = f / DD;
        int s, d;
        if (e < NEDGES) { s = src[e]; d = dst[e]; } else { s = e - NEDGES; d = s; }
        float w = exw[e * HH + h] / den[d * HH + h];
        atomicAdd(&out[(long long)d * F + f], w * Hb[(long long)s * F + f]);
    }
}

// ---------------- elementwise bias (+optional relu), in place ----------------
__global__ void bias_act(float* __restrict__ y, const float* __restrict__ b, int n, int F,
                         int relu) {
    int idx = blockIdx.x * blockDim.x + threadIdx.x;
    if (idx >= n * F) return;
    int f = idx % F;
    float v = y[idx] + b[f];
    if (relu) v = fmaxf(v, 0.f);
    y[idx] = v;
}

// ---------------- batchnorm stats: sums[0..F)=sum, sums[F..2F)=sumsq ----------------
__global__ void bn_stats(const float* __restrict__ x, float* __restrict__ sums, int n, int F) {
    int f = threadIdx.x % F;
    int rpb = blockDim.x / F;
    int r0 = blockIdx.x * rpb + threadIdx.x / F;
    float s = 0.f, s2 = 0.f;
    for (int r = r0; r < n; r += gridDim.x * rpb) {
        float v = x[r * F + f];
        s += v;
        s2 += v * v;
    }
    atomicAdd(&sums[f], s);
    atomicAdd(&sums[F + f], s2);
}

// ---------------- batchnorm normalize (+optional relu), in place ----------------
__global__ void bn_norm(float* __restrict__ y, const float* __restrict__ sums,
                        const float* __restrict__ gamma, const float* __restrict__ beta, int n,
                        int F, int relu) {
    int idx = blockIdx.x * blockDim.x + threadIdx.x;
    if (idx >= n * F) return;
    int f = idx % F;
    float mu = sums[f] / (float)n;
    float var = sums[F + f] / (float)n - mu * mu;
    float v = (y[idx] - mu) * rsqrtf(var + BN_EPS) * gamma[f] + beta[f];
    if (relu) v = fmaxf(v, 0.f);
    y[idx] = v;
}

extern "C" void kernel_launch(void* const* d_in, const int* in_sizes, int n_in, void* d_out,
                              int out_size, void* d_ws, size_t ws_size, hipStream_t stream) {
    const int N = NNODES, E = NEDGES;
    const float* x = (const float*)d_in[0];
    const int* ei = (const int*)d_in[1];
    const int* src = ei;
    const int* dst = ei + E;
    const float* W1 = (const float*)d_in[2];
    const float* as1 = (const float*)d_in[3];
    const float* ad1 = (const float*)d_in[4];
    const float* b1 = (const float*)d_in[5];
    const float* g1 = (const float*)d_in[6];
    const float* be1 = (const float*)d_in[7];
    const float* W2 = (const float*)d_in[8];
    const float* as2 = (const float*)d_in[9];
    const float* ad2 = (const float*)d_in[10];
    const float* b2 = (const float*)d_in[11];
    const float* g2 = (const float*)d_in[12];
    const float* be2 = (const float*)d_in[13];
    const float* W3 = (const float*)d_in[14];
    const float* as3 = (const float*)d_in[15];
    const float* ad3 = (const float*)d_in[16];
    const float* b3 = (const float*)d_in[17];
    const float* W4 = (const float*)d_in[18];
    const float* as4 = (const float*)d_in[19];
    const float* ad4 = (const float*)d_in[20];
    const float* b4 = (const float*)d_in[21];
    const float* g4 = (const float*)d_in[22];
    const float* be4 = (const float*)d_in[23];
    const float* W5 = (const float*)d_in[24];
    const float* as5 = (const float*)d_in[25];
    const float* ad5 = (const float*)d_in[26];
    const float* b5 = (const float*)d_in[27];
    float* out = (float*)d_out;

    // workspace layout (floats)
    float* ws = (float*)d_ws;
    float* bufA = ws;                       // N*128  (matmul output h)
    float* bufB = ws + (size_t)N * 128;     // N*128  (aggregation output / layer activations)
    float* es = ws + (size_t)2 * N * 128;   // N*4
    float* ed = es + (size_t)N * 4;         // N*4
    float* den = ed + (size_t)N * 4;        // N*4
    float* exw = den + (size_t)N * 4;       // (E+N)*4
    float* sums = exw + (size_t)(E + N) * 4;  // 256

    const dim3 mmB(16, 16);
    const int TB = 256;
    const int gNF128 = (N * 128 + TB - 1) / TB;
    const int gNF32 = (N * 32 + TB - 1) / TB;

    // ================= GAT1: 128 -> 4x32, relu, bn =================
    matmul16<<<dim3(3125, 8), mmB, 0, stream>>>(x, W1, bufA, N, 128, 128);
    attn_scores<4, 32><<<(N * 4 + TB - 1) / TB, TB, 0, stream>>>(bufA, as1, ad1, es, ed);
    hipMemsetAsync(den, 0, (size_t)N * 4 * sizeof(float), stream);
    hipMemsetAsync(bufB, 0, (size_t)N * 128 * sizeof(float), stream);
    edge_ex<4><<<8192, TB, 0, stream>>>(src, dst, es, ed, exw, den);
    edge_agg<4, 32><<<16384, TB, 0, stream>>>(src, dst, bufA, exw, den, bufB);
    bias_act<<<gNF128, TB, 0, stream>>>(bufB, b1, N, 128, 1);
    hipMemsetAsync(sums, 0, 256 * sizeof(float), stream);
    bn_stats<<<256, TB, 0, stream>>>(bufB, sums, N, 128);
    bn_norm<<<gNF128, TB, 0, stream>>>(bufB, sums, g1, be1, N, 128, 0);

    // ================= GAT2: 128 -> 4x32, relu, bn =================
    matmul16<<<dim3(3125, 8), mmB, 0, stream>>>(bufB, W2, bufA, N, 128, 128);
    attn_scores<4, 32><<<(N * 4 + TB - 1) / TB, TB, 0, stream>>>(bufA, as2, ad2, es, ed);
    hipMemsetAsync(den, 0, (size_t)N * 4 * sizeof(float), stream);
    hipMemsetAsync(bufB, 0, (size_t)N * 128 * sizeof(float), stream);
    edge_ex<4><<<8192, TB, 0, stream>>>(src, dst, es, ed, exw, den);
    edge_agg<4, 32><<<16384, TB, 0, stream>>>(src, dst, bufA, exw, den, bufB);
    bias_act<<<gNF128, TB, 0, stream>>>(bufB, b2, N, 128, 1);
    hipMemsetAsync(sums, 0, 256 * sizeof(float), stream);
    bn_stats<<<256, TB, 0, stream>>>(bufB, sums, N, 128);
    bn_norm<<<gNF128, TB, 0, stream>>>(bufB, sums, g2, be2, N, 128, 0);

    // ================= GAT3: 128 -> 32 (1 head), relu =================
    matmul16<<<dim3(3125, 2), mmB, 0, stream>>>(bufB, W3, bufA, N, 128, 32);
    attn_scores<1, 32><<<(N + TB - 1) / TB, TB, 0, stream>>>(bufA, as3, ad3, es, ed);
    hipMemsetAsync(den, 0, (size_t)N * sizeof(float), stream);
    hipMemsetAsync(bufB, 0, (size_t)N * 32 * sizeof(float), stream);
    edge_ex<1><<<4096, TB, 0, stream>>>(src, dst, es, ed, exw, den);
    edge_agg<1, 32><<<8192, TB, 0, stream>>>(src, dst, bufA, exw, den, bufB);
    bias_act<<<gNF32, TB, 0, stream>>>(bufB, b3, N, 32, 1);

    // ================= GAT4: 32 -> 32 (1 head), relu, bn, relu =================
    matmul16<<<dim3(3125, 2), mmB, 0, stream>>>(bufB, W4, bufA, N, 32, 32);
    attn_scores<1, 32><<<(N + TB - 1) / TB, TB, 0, stream>>>(bufA, as4, ad4, es, ed);
    hipMemsetAsync(den, 0, (size_t)N * sizeof(float), stream);
    hipMemsetAsync(bufB, 0, (size_t)N * 32 * sizeof(float), stream);
    edge_ex<1><<<4096, TB, 0, stream>>>(src, dst, es, ed, exw, den);
    edge_agg<1, 32><<<8192, TB, 0, stream>>>(src, dst, bufA, exw, den, bufB);
    bias_act<<<gNF32, TB, 0, stream>>>(bufB, b4, N, 32, 1);
    hipMemsetAsync(sums, 0, 256 * sizeof(float), stream);
    bn_stats<<<256, TB, 0, stream>>>(bufB, sums, N, 32);
    bn_norm<<<gNF32, TB, 0, stream>>>(bufB, sums, g4, be4, N, 32, 1);

    // ================= GAT5: 32 -> 128 (1 head), no act =================
    matmul16<<<dim3(3125, 8), mmB, 0, stream>>>(bufB, W5, bufA, N, 32, 128);
    attn_scores<1, 128><<<(N + TB - 1) / TB, TB, 0, stream>>>(bufA, as5, ad5, es, ed);
    hipMemsetAsync(den, 0, (size_t)N * sizeof(float), stream);
    hipMemsetAsync(out, 0, (size_t)N * 128 * sizeof(float), stream);
    edge_ex<1><<<4096, TB, 0, stream>>>(src, dst, es, ed, exw, den);
    edge_agg<1, 128><<<16384, TB, 0, stream>>>(src, dst, bufA, exw, den, out);
    bias_act<<<gNF128, TB, 0, stream>>>(out, b5, N, 128, 0);
}

// Round 2
// 942.880 us; speedup vs baseline: 2.3412x; 2.3412x over previous
//
#include <hip/hip_runtime.h>
#include <math.h>

#define NNODES 50000
#define NEDGES 800000
#define BN_EPS 1e-5f
#define DEGC 128   // LDS-cached in-edges per node; fallback path beyond

// ================= counting sort by dst =================
__global__ void deg_init(int* __restrict__ cnt) {
    int i = blockIdx.x * blockDim.x + threadIdx.x;
    if (i < NNODES) cnt[i] = 1;  // self-loop
}

__global__ void hist_dst(const int* __restrict__ dst, int* __restrict__ cnt) {
    int e = blockIdx.x * blockDim.x + threadIdx.x;
    if (e < NEDGES) atomicAdd(&cnt[dst[e]], 1);
}

// single-block exclusive scan of cnt[0..N) -> off[0..N]
__global__ void scan50k(const int* __restrict__ cnt, int* __restrict__ off) {
    __shared__ int buf[1024];
    int carry = 0;
    for (int base = 0; base < NNODES; base += 1024) {
        int i = base + threadIdx.x;
        int v = (i < NNODES) ? cnt[i] : 0;
        buf[threadIdx.x] = v;
        __syncthreads();
        int x = v;
        for (int s = 1; s < 1024; s <<= 1) {
            int t = (threadIdx.x >= s) ? buf[threadIdx.x - s] : 0;
            __syncthreads();
            x += t;
            buf[threadIdx.x] = x;
            __syncthreads();
        }
        if (i < NNODES) off[i] = carry + x - v;
        int tot = buf[1023];
        __syncthreads();
        carry += tot;
    }
    if (threadIdx.x == 0) off[NNODES] = carry;  // == NEDGES + NNODES
}

__global__ void scatter_edges(const int* __restrict__ src, const int* __restrict__ dst,
                              const int* __restrict__ off, int* __restrict__ cur,
                              int* __restrict__ ssorted) {
    int e = blockIdx.x * blockDim.x + threadIdx.x;
    if (e < NEDGES) {
        int d = dst[e];
        int p = off[d] + atomicAdd(&cur[d], 1);
        ssorted[p] = src[e];
    }
}

__global__ void self_loops(const int* __restrict__ off, int* __restrict__ ssorted) {
    int d = blockIdx.x * blockDim.x + threadIdx.x;
    if (d < NNODES) ssorted[off[d + 1] - 1] = d;  // last slot of each segment
}

// ================= dense matmul: O[N,F] = X[N,K] @ W[K,F], 64xBN tile, 4x(BN/16)/thread =================
template <int BN>
__global__ __launch_bounds__(256) void matmul_rt(const float* __restrict__ X,
                                                 const float* __restrict__ W,
                                                 float* __restrict__ O, int N, int K, int F) {
    constexpr int TN = BN / 16;
    __shared__ float sX[16][64 + 4];
    __shared__ float sW[16][BN + 4];
    int tid = threadIdx.x;
    int rowBase = blockIdx.x * 64, colBase = blockIdx.y * BN;
    int tr = (tid >> 4) * 4, tc = (tid & 15) * TN;
    float acc[4][TN];
#pragma unroll
    for (int x = 0; x < 4; ++x)
#pragma unroll
        for (int y = 0; y < TN; ++y) acc[x][y] = 0.f;

    for (int k0 = 0; k0 < K; k0 += 16) {
        for (int i = tid; i < 64 * 16; i += 256) {
            int r = i >> 4, k = i & 15;
            int gr = rowBase + r;
            sX[k][r] = (gr < N) ? X[(size_t)gr * K + k0 + k] : 0.f;
        }
        for (int i = tid; i < 16 * BN; i += 256) {
            int k = i / BN, c = i % BN;
            sW[k][c] = W[(size_t)(k0 + k) * F + colBase + c];
        }
        __syncthreads();
#pragma unroll
        for (int k = 0; k < 16; ++k) {
            float4 av = *(const float4*)&sX[k][tr];
            float a[4] = {av.x, av.y, av.z, av.w};
            float b[TN];
            if constexpr (TN == 4) {
                float4 bv = *(const float4*)&sW[k][tc];
                b[0] = bv.x; b[1] = bv.y; b[2] = bv.z; b[3] = bv.w;
            } else {
                float2 bv = *(const float2*)&sW[k][tc];
                b[0] = bv.x; b[1] = bv.y;
            }
#pragma unroll
            for (int x = 0; x < 4; ++x)
#pragma unroll
                for (int y = 0; y < TN; ++y) acc[x][y] += a[x] * b[y];
        }
        __syncthreads();
    }
#pragma unroll
    for (int x = 0; x < 4; ++x) {
        int gr = rowBase + tr + x;
        if (gr < N)
#pragma unroll
            for (int y = 0; y < TN; ++y) O[(size_t)gr * F + colBase + tc + y] = acc[x][y];
    }
}

// ================= per-node attention scores =================
template <int HH, int DD>
__global__ void attn_scores(const float* __restrict__ Hb, const float* __restrict__ asrc,
                            const float* __restrict__ adst, float* __restrict__ es,
                            float* __restrict__ ed) {
    int idx = blockIdx.x * blockDim.x + threadIdx.x;
    if (idx >= NNODES * HH) return;
    int h = idx % HH;
    const float4* hp = (const float4*)(Hb + (size_t)idx * DD);
    const float4* ap = (const float4*)(asrc + h * DD);
    const float4* bp = (const float4*)(adst + h * DD);
    float s = 0.f, t = 0.f;
#pragma unroll
    for (int q = 0; q < DD / 4; ++q) {
        float4 v = hp[q], a = ap[q], b = bp[q];
        s += v.x * a.x + v.y * a.y + v.z * a.z + v.w * a.w;
        t += v.x * b.x + v.y * b.y + v.z * b.z + v.w * b.w;
    }
    es[idx] = s;
    ed[idx] = t;
}

// ================= gather-style softmax-aggregate: one wave per dst node =================
// out[d,f] = bias[f] + sum_e w_e * h[src_e, f],  w_e = ex_e / den_d   (+optional relu)
template <int HH, int DD>
__global__ __launch_bounds__(256) void node_agg(const int* __restrict__ off,
                                                const int* __restrict__ ssorted,
                                                const float* __restrict__ Hb,
                                                const float* __restrict__ es,
                                                const float* __restrict__ ed,
                                                const float* __restrict__ bias,
                                                float* __restrict__ outp, int relu) {
    constexpr int F = HH * DD;
    __shared__ float lds_ex[4][DEGC * HH];
    __shared__ int lds_s[4][DEGC];
    int wib = threadIdx.x >> 6;
    int lane = threadIdx.x & 63;
    int d = blockIdx.x * 4 + wib;  // grid is exactly N waves
    int beg = off[d], end = off[d + 1];
    int m = end - beg;  // >= 1 (self loop)

    float edv[HH];
#pragma unroll
    for (int h = 0; h < HH; ++h) edv[h] = ed[(size_t)d * HH + h];
    float denp[HH];
#pragma unroll
    for (int h = 0; h < HH; ++h) denp[h] = 0.f;

    // pass 1: ex per edge (-> LDS), denominator partials
    for (int base = 0; base < m; base += 64) {
        int i = base + lane;
        if (i < m) {
            int s = ssorted[beg + i];
            if (i < DEGC) lds_s[wib][i] = s;
#pragma unroll
            for (int h = 0; h < HH; ++h) {
                float a = es[(size_t)s * HH + h] + edv[h];
                a = a > 0.f ? a : 0.2f * a;
                float ex = __expf(a);
                denp[h] += ex;
                if (i < DEGC) lds_ex[wib][i * HH + h] = ex;
            }
        }
    }
#pragma unroll
    for (int h = 0; h < HH; ++h)
#pragma unroll
        for (int sft = 1; sft < 64; sft <<= 1) denp[h] += __shfl_xor(denp[h], sft);

    __syncthreads();  // LDS visibility (block has exactly 4 live waves)

    if constexpr (F == 128) {
        int h0, h1;
        float den0, den1, ed0, ed1;
        if constexpr (HH == 4) {
            h0 = lane >> 5;
            h1 = 2 + (lane >> 5);
            den0 = (lane < 32) ? denp[0] : denp[1];
            den1 = (lane < 32) ? denp[2] : denp[3];
            ed0 = (lane < 32) ? edv[0] : edv[1];
            ed1 = (lane < 32) ? edv[2] : edv[3];
        } else {
            h0 = 0; h1 = 0;
            den0 = denp[0]; den1 = denp[0];
            ed0 = edv[0]; ed1 = edv[0];
        }
        float inv0 = 1.f / den0, inv1 = 1.f / den1;
        int f0 = lane, f1 = lane + 64;
        float acc0 = 0.f, acc1 = 0.f;
        for (int i = 0; i < m; ++i) {
            int s;
            float ex0, ex1;
            if (i < DEGC) {
                s = lds_s[wib][i];
                ex0 = lds_ex[wib][i * HH + h0];
                ex1 = lds_ex[wib][i * HH + h1];
            } else {  // rare high-degree fallback
                s = ssorted[beg + i];
                float a0 = es[(size_t)s * HH + h0] + ed0;
                a0 = a0 > 0.f ? a0 : 0.2f * a0;
                ex0 = __expf(a0);
                float a1 = es[(size_t)s * HH + h1] + ed1;
                a1 = a1 > 0.f ? a1 : 0.2f * a1;
                ex1 = __expf(a1);
            }
            const float* hp = Hb + (size_t)s * F;
            acc0 += ex0 * inv0 * hp[f0];
            acc1 += ex1 * inv1 * hp[f1];
        }
        float v0 = acc0 + bias[f0];
        float v1 = acc1 + bias[f1];
        if (relu) { v0 = fmaxf(v0, 0.f); v1 = fmaxf(v1, 0.f); }
        outp[(size_t)d * F + f0] = v0;
        outp[(size_t)d * F + f1] = v1;
    } else {
        // F == 32, HH == 1: two half-waves split the edges
        int sub = lane >> 5, f = lane & 31;
        float inv = 1.f / denp[0];
        float acc = 0.f;
        for (int i = sub; i < m; i += 2) {
            int s;
            float ex;
            if (i < DEGC) {
                s = lds_s[wib][i];
                ex = lds_ex[wib][i];
            } else {
                s = ssorted[beg + i];
                float a = es[s] + edv[0];
                a = a > 0.f ? a : 0.2f * a;
                ex = __expf(a);
            }
            acc += ex * inv * Hb[(size_t)s * 32 + f];
        }
        acc += __shfl_xor(acc, 32);
        if (sub == 0) {
            float v = acc + bias[f];
            if (relu) v = fmaxf(v, 0.f);
            outp[(size_t)d * 32 + f] = v;
        }
    }
}

// ================= batchnorm =================
__global__ void bn_stats(const float* __restrict__ x, float* __restrict__ sums, int n, int F) {
    int f = threadIdx.x % F;
    int rpb = blockDim.x / F;
    int r0 = blockIdx.x * rpb + threadIdx.x / F;
    float s = 0.f, s2 = 0.f;
    for (int r = r0; r < n; r += gridDim.x * rpb) {
        float v = x[r * F + f];
        s += v;
        s2 += v * v;
    }
    atomicAdd(&sums[f], s);
    atomicAdd(&sums[F + f], s2);
}

__global__ void bn_norm(float* __restrict__ y, const float* __restrict__ sums,
                        const float* __restrict__ gamma, const float* __restrict__ beta, int n,
                        int F, int relu) {
    int idx = blockIdx.x * blockDim.x + threadIdx.x;
    if (idx >= n * F) return;
    int f = idx % F;
    float mu = sums[f] / (float)n;
    float var = sums[F + f] / (float)n - mu * mu;
    float v = (y[idx] - mu) * rsqrtf(var + BN_EPS) * gamma[f] + beta[f];
    if (relu) v = fmaxf(v, 0.f);
    y[idx] = v;
}

extern "C" void kernel_launch(void* const* d_in, const int* in_sizes, int n_in, void* d_out,
                              int out_size, void* d_ws, size_t ws_size, hipStream_t stream) {
    const int N = NNODES, E = NEDGES;
    const float* x = (const float*)d_in[0];
    const int* ei = (const int*)d_in[1];
    const int* src = ei;
    const int* dst = ei + E;
    const float* W1 = (const float*)d_in[2];
    const float* as1 = (const float*)d_in[3];
    const float* ad1 = (const float*)d_in[4];
    const float* b1 = (const float*)d_in[5];
    const float* g1 = (const float*)d_in[6];
    const float* be1 = (const float*)d_in[7];
    const float* W2 = (const float*)d_in[8];
    const float* as2 = (const float*)d_in[9];
    const float* ad2 = (const float*)d_in[10];
    const float* b2 = (const float*)d_in[11];
    const float* g2 = (const float*)d_in[12];
    const float* be2 = (const float*)d_in[13];
    const float* W3 = (const float*)d_in[14];
    const float* as3 = (const float*)d_in[15];
    const float* ad3 = (const float*)d_in[16];
    const float* b3 = (const float*)d_in[17];
    const float* W4 = (const float*)d_in[18];
    const float* as4 = (const float*)d_in[19];
    const float* ad4 = (const float*)d_in[20];
    const float* b4 = (const float*)d_in[21];
    const float* g4 = (const float*)d_in[22];
    const float* be4 = (const float*)d_in[23];
    const float* W5 = (const float*)d_in[24];
    const float* as5 = (const float*)d_in[25];
    const float* ad5 = (const float*)d_in[26];
    const float* b5 = (const float*)d_in[27];
    float* out = (float*)d_out;

    // workspace layout
    float* ws = (float*)d_ws;
    float* bufA = ws;                          // N*128 (matmul out)
    float* bufB = ws + (size_t)N * 128;        // N*128 (layer activation)
    float* es = ws + (size_t)2 * N * 128;      // N*4
    float* ed = es + (size_t)N * 4;            // N*4
    float* sums = ed + (size_t)N * 4;          // 256
    int* cnt = (int*)(sums + 256);             // N
    int* off = cnt + N;                        // N+1
    int* cur = off + N + 1;                    // N
    int* ssorted = cur + N;                    // E+N

    const int TB = 256;
    const int gE = (E + TB - 1) / TB;
    const int gN = (N + TB - 1) / TB;
    const int gNF128 = (N * 128 + TB - 1) / TB;
    const int gNF32 = (N * 32 + TB - 1) / TB;
    const int gAgg = N / 4;  // 4 waves/block, N == 50000 divisible by 4
    const dim3 mmGrid128((N + 63) / 64, 2);
    const dim3 mmGrid32((N + 63) / 64, 1);

    // ---- one-time CSR-by-dst build ----
    deg_init<<<gN, TB, 0, stream>>>(cnt);
    hist_dst<<<gE, TB, 0, stream>>>(dst, cnt);
    scan50k<<<1, 1024, 0, stream>>>(cnt, off);
    hipMemsetAsync(cur, 0, (size_t)N * sizeof(int), stream);
    scatter_edges<<<gE, TB, 0, stream>>>(src, dst, off, cur, ssorted);
    self_loops<<<gN, TB, 0, stream>>>(off, ssorted);

    // ================= GAT1: 128 -> 4x32, relu, bn =================
    matmul_rt<64><<<mmGrid128, TB, 0, stream>>>(x, W1, bufA, N, 128, 128);
    attn_scores<4, 32><<<(N * 4 + TB - 1) / TB, TB, 0, stream>>>(bufA, as1, ad1, es, ed);
    node_agg<4, 32><<<gAgg, TB, 0, stream>>>(off, ssorted, bufA, es, ed, b1, bufB, 1);
    hipMemsetAsync(sums, 0, 256 * sizeof(float), stream);
    bn_stats<<<256, TB, 0, stream>>>(bufB, sums, N, 128);
    bn_norm<<<gNF128, TB, 0, stream>>>(bufB, sums, g1, be1, N, 128, 0);

    // ================= GAT2: 128 -> 4x32, relu, bn =================
    matmul_rt<64><<<mmGrid128, TB, 0, stream>>>(bufB, W2, bufA, N, 128, 128);
    attn_scores<4, 32><<<(N * 4 + TB - 1) / TB, TB, 0, stream>>>(bufA, as2, ad2, es, ed);
    node_agg<4, 32><<<gAgg, TB, 0, stream>>>(off, ssorted, bufA, es, ed, b2, bufB, 1);
    hipMemsetAsync(sums, 0, 256 * sizeof(float), stream);
    bn_stats<<<256, TB, 0, stream>>>(bufB, sums, N, 128);
    bn_norm<<<gNF128, TB, 0, stream>>>(bufB, sums, g2, be2, N, 128, 0);

    // ================= GAT3: 128 -> 32, relu =================
    matmul_rt<32><<<mmGrid32, TB, 0, stream>>>(bufB, W3, bufA, N, 128, 32);
    attn_scores<1, 32><<<gN, TB, 0, stream>>>(bufA, as3, ad3, es, ed);
    node_agg<1, 32><<<gAgg, TB, 0, stream>>>(off, ssorted, bufA, es, ed, b3, bufB, 1);

    // ================= GAT4: 32 -> 32, relu, bn, relu =================
    matmul_rt<32><<<mmGrid32, TB, 0, stream>>>(bufB, W4, bufA, N, 32, 32);
    attn_scores<1, 32><<<gN, TB, 0, stream>>>(bufA, as4, ad4, es, ed);
    node_agg<1, 32><<<gAgg, TB, 0, stream>>>(off, ssorted, bufA, es, ed, b4, bufB, 1);
    hipMemsetAsync(sums, 0, 256 * sizeof(float), stream);
    bn_stats<<<256, TB, 0, stream>>>(bufB, sums, N, 32);
    bn_norm<<<gNF32, TB, 0, stream>>>(bufB, sums, g4, be4, N, 32, 1);

    // ================= GAT5: 32 -> 128, no act =================
    matmul_rt<64><<<mmGrid128, TB, 0, stream>>>(bufB, W5, bufA, N, 32, 128);
    attn_scores<1, 128><<<gN, TB, 0, stream>>>(bufA, as5, ad5, es, ed);
    node_agg<1, 128><<<gAgg, TB, 0, stream>>>(off, ssorted, bufA, es, ed, b5, out, 0);
}

// Round 3
// 788.171 us; speedup vs baseline: 2.8008x; 1.1963x over previous
//
#include <hip/hip_runtime.h>
#include <math.h>

#define NNODES 50000
#define NEDGES 800000
#define BN_EPS 1e-5f
#define DEGC 128   // LDS-cached in-edges per node; fallback path beyond

// ================= counting sort by dst =================
__global__ void deg_init(int* __restrict__ cnt) {
    int i = blockIdx.x * blockDim.x + threadIdx.x;
    if (i < NNODES) cnt[i] = 1;  // self-loop
}

__global__ void hist_dst(const int* __restrict__ dst, int* __restrict__ cnt) {
    int e = blockIdx.x * blockDim.x + threadIdx.x;
    if (e < NEDGES) atomicAdd(&cnt[dst[e]], 1);
}

// single-block exclusive scan of cnt[0..N) -> off[0..N], shfl-based wave scan
__global__ void scan50k(const int* __restrict__ cnt, int* __restrict__ off) {
    __shared__ int wsum[16];
    int lane = threadIdx.x & 63, wid = threadIdx.x >> 6;
    int carry = 0;
    for (int base = 0; base < NNODES; base += 1024) {
        int i = base + threadIdx.x;
        int v = (i < NNODES) ? cnt[i] : 0;
        int x = v;
#pragma unroll
        for (int s = 1; s < 64; s <<= 1) {
            int t = __shfl_up(x, s);
            if (lane >= s) x += t;
        }
        if (lane == 63) wsum[wid] = x;
        __syncthreads();
        if (wid == 0) {
            int w = (lane < 16) ? wsum[lane] : 0;
#pragma unroll
            for (int s = 1; s < 16; s <<= 1) {
                int t = __shfl_up(w, s);
                if (lane >= s) w += t;
            }
            if (lane < 16) wsum[lane] = w;  // inclusive scan of wave sums
        }
        __syncthreads();
        int woff = (wid > 0) ? wsum[wid - 1] : 0;
        int incl = x + woff;
        if (i < NNODES) off[i] = carry + incl - v;
        int tot = wsum[15];
        __syncthreads();
        carry += tot;
    }
    if (threadIdx.x == 0) off[NNODES] = carry;  // == NEDGES + NNODES
}

__global__ void scatter_edges(const int* __restrict__ src, const int* __restrict__ dst,
                              const int* __restrict__ off, int* __restrict__ cur,
                              int* __restrict__ ssorted) {
    int e = blockIdx.x * blockDim.x + threadIdx.x;
    if (e < NEDGES) {
        int d = dst[e];
        int p = off[d] + atomicAdd(&cur[d], 1);
        ssorted[p] = src[e];
    }
}

__global__ void self_loops(const int* __restrict__ off, int* __restrict__ ssorted) {
    int d = blockIdx.x * blockDim.x + threadIdx.x;
    if (d < NNODES) ssorted[off[d + 1] - 1] = d;  // last slot of each segment
}

// ================= dense matmul: O[N,F] = X[N,K] @ W[K,F], 64xBN tile =================
template <int BN>
__global__ __launch_bounds__(256) void matmul_rt(const float* __restrict__ X,
                                                 const float* __restrict__ W,
                                                 float* __restrict__ O, int N, int K, int F) {
    constexpr int TN = BN / 16;
    __shared__ float sX[16][64 + 4];
    __shared__ float sW[16][BN + 4];
    int tid = threadIdx.x;
    int rowBase = blockIdx.x * 64, colBase = blockIdx.y * BN;
    int tr = (tid >> 4) * 4, tc = (tid & 15) * TN;
    float acc[4][TN];
#pragma unroll
    for (int x = 0; x < 4; ++x)
#pragma unroll
        for (int y = 0; y < TN; ++y) acc[x][y] = 0.f;

    for (int k0 = 0; k0 < K; k0 += 16) {
        for (int i = tid; i < 64 * 16; i += 256) {
            int r = i >> 4, k = i & 15;
            int gr = rowBase + r;
            sX[k][r] = (gr < N) ? X[(size_t)gr * K + k0 + k] : 0.f;
        }
        for (int i = tid; i < 16 * BN; i += 256) {
            int k = i / BN, c = i % BN;
            sW[k][c] = W[(size_t)(k0 + k) * F + colBase + c];
        }
        __syncthreads();
#pragma unroll
        for (int k = 0; k < 16; ++k) {
            float4 av = *(const float4*)&sX[k][tr];
            float a[4] = {av.x, av.y, av.z, av.w};
            float b[TN];
            if constexpr (TN == 4) {
                float4 bv = *(const float4*)&sW[k][tc];
                b[0] = bv.x; b[1] = bv.y; b[2] = bv.z; b[3] = bv.w;
            } else {
                float2 bv = *(const float2*)&sW[k][tc];
                b[0] = bv.x; b[1] = bv.y;
            }
#pragma unroll
            for (int x = 0; x < 4; ++x)
#pragma unroll
                for (int y = 0; y < TN; ++y) acc[x][y] += a[x] * b[y];
        }
        __syncthreads();
    }
#pragma unroll
    for (int x = 0; x < 4; ++x) {
        int gr = rowBase + tr + x;
        if (gr < N)
#pragma unroll
            for (int y = 0; y < TN; ++y) O[(size_t)gr * F + colBase + tc + y] = acc[x][y];
    }
}

// ================= per-node attention scores =================
template <int HH, int DD>
__global__ void attn_scores(const float* __restrict__ Hb, const float* __restrict__ asrc,
                            const float* __restrict__ adst, float* __restrict__ es,
                            float* __restrict__ ed) {
    int idx = blockIdx.x * blockDim.x + threadIdx.x;
    if (idx >= NNODES * HH) return;
    int h = idx % HH;
    const float4* hp = (const float4*)(Hb + (size_t)idx * DD);
    const float4* ap = (const float4*)(asrc + h * DD);
    const float4* bp = (const float4*)(adst + h * DD);
    float s = 0.f, t = 0.f;
#pragma unroll
    for (int q = 0; q < DD / 4; ++q) {
        float4 v = hp[q], a = ap[q], b = bp[q];
        s += v.x * a.x + v.y * a.y + v.z * a.z + v.w * a.w;
        t += v.x * b.x + v.y * b.y + v.z * b.z + v.w * b.w;
    }
    es[idx] = s;
    ed[idx] = t;
}

// ================= gather-style softmax-aggregate: one wave per dst node =================
template <int HH, int DD>
__global__ __launch_bounds__(256) void node_agg(const int* __restrict__ off,
                                                const int* __restrict__ ssorted,
                                                const float* __restrict__ Hb,
                                                const float* __restrict__ es,
                                                const float* __restrict__ ed,
                                                const float* __restrict__ bias,
                                                float* __restrict__ outp, int relu) {
    constexpr int F = HH * DD;
    __shared__ float lds_ex[4][DEGC * HH];
    __shared__ int lds_s[4][DEGC];
    int wib = threadIdx.x >> 6;
    int lane = threadIdx.x & 63;
    int d = blockIdx.x * 4 + wib;  // grid is exactly N waves
    int beg = off[d], end = off[d + 1];
    int m = end - beg;  // >= 1 (self loop)

    float edv[HH];
#pragma unroll
    for (int h = 0; h < HH; ++h) edv[h] = ed[(size_t)d * HH + h];
    float denp[HH];
#pragma unroll
    for (int h = 0; h < HH; ++h) denp[h] = 0.f;

    for (int base = 0; base < m; base += 64) {
        int i = base + lane;
        if (i < m) {
            int s = ssorted[beg + i];
            if (i < DEGC) lds_s[wib][i] = s;
#pragma unroll
            for (int h = 0; h < HH; ++h) {
                float a = es[(size_t)s * HH + h] + edv[h];
                a = a > 0.f ? a : 0.2f * a;
                float ex = __expf(a);
                denp[h] += ex;
                if (i < DEGC) lds_ex[wib][i * HH + h] = ex;
            }
        }
    }
#pragma unroll
    for (int h = 0; h < HH; ++h)
#pragma unroll
        for (int sft = 1; sft < 64; sft <<= 1) denp[h] += __shfl_xor(denp[h], sft);

    __syncthreads();

    if constexpr (F == 128) {
        int h0, h1;
        float den0, den1, ed0, ed1;
        if constexpr (HH == 4) {
            h0 = lane >> 5;
            h1 = 2 + (lane >> 5);
            den0 = (lane < 32) ? denp[0] : denp[1];
            den1 = (lane < 32) ? denp[2] : denp[3];
            ed0 = (lane < 32) ? edv[0] : edv[1];
            ed1 = (lane < 32) ? edv[2] : edv[3];
        } else {
            h0 = 0; h1 = 0;
            den0 = denp[0]; den1 = denp[0];
            ed0 = edv[0]; ed1 = edv[0];
        }
        float inv0 = 1.f / den0, inv1 = 1.f / den1;
        int f0 = lane, f1 = lane + 64;
        float acc0 = 0.f, acc1 = 0.f;
        for (int i = 0; i < m; ++i) {
            int s;
            float ex0, ex1;
            if (i < DEGC) {
                s = lds_s[wib][i];
                ex0 = lds_ex[wib][i * HH + h0];
                ex1 = lds_ex[wib][i * HH + h1];
            } else {
                s = ssorted[beg + i];
                float a0 = es[(size_t)s * HH + h0] + ed0;
                a0 = a0 > 0.f ? a0 : 0.2f * a0;
                ex0 = __expf(a0);
                float a1 = es[(size_t)s * HH + h1] + ed1;
                a1 = a1 > 0.f ? a1 : 0.2f * a1;
                ex1 = __expf(a1);
            }
            const float* hp = Hb + (size_t)s * F;
            acc0 += ex0 * inv0 * hp[f0];
            acc1 += ex1 * inv1 * hp[f1];
        }
        float v0 = acc0 + bias[f0];
        float v1 = acc1 + bias[f1];
        if (relu) { v0 = fmaxf(v0, 0.f); v1 = fmaxf(v1, 0.f); }
        outp[(size_t)d * F + f0] = v0;
        outp[(size_t)d * F + f1] = v1;
    } else {
        int sub = lane >> 5, f = lane & 31;
        float inv = 1.f / denp[0];
        float acc = 0.f;
        for (int i = sub; i < m; i += 2) {
            int s;
            float ex;
            if (i < DEGC) {
                s = lds_s[wib][i];
                ex = lds_ex[wib][i];
            } else {
                s = ssorted[beg + i];
                float a = es[s] + edv[0];
                a = a > 0.f ? a : 0.2f * a;
                ex = __expf(a);
            }
            acc += ex * inv * Hb[(size_t)s * 32 + f];
        }
        acc += __shfl_xor(acc, 32);
        if (sub == 0) {
            float v = acc + bias[f];
            if (relu) v = fmaxf(v, 0.f);
            outp[(size_t)d * 32 + f] = v;
        }
    }
}

// ================= batchnorm stats: float4/thread, LDS block-reduce, 1 atomic/feat/block =================
template <int F>
__global__ __launch_bounds__(256) void bn_stats(const float* __restrict__ x,
                                                float* __restrict__ sums, int n) {
    constexpr int TPR = F / 4;        // threads per row
    constexpr int RPB = 256 / TPR;    // rows per block-iteration
    __shared__ float ls[2 * F];
    if (threadIdx.x < 2 * F) ls[threadIdx.x] = 0.f;
    int tf = threadIdx.x % TPR;
    int tr = threadIdx.x / TPR;
    float4 s = make_float4(0.f, 0.f, 0.f, 0.f), q = make_float4(0.f, 0.f, 0.f, 0.f);
    for (int r = blockIdx.x * RPB + tr; r < n; r += gridDim.x * RPB) {
        float4 v = *(const float4*)(x + (size_t)r * F + tf * 4);
        s.x += v.x; s.y += v.y; s.z += v.z; s.w += v.w;
        q.x += v.x * v.x; q.y += v.y * v.y; q.z += v.z * v.z; q.w += v.w * v.w;
    }
    __syncthreads();
    atomicAdd(&ls[tf * 4 + 0], s.x);
    atomicAdd(&ls[tf * 4 + 1], s.y);
    atomicAdd(&ls[tf * 4 + 2], s.z);
    atomicAdd(&ls[tf * 4 + 3], s.w);
    atomicAdd(&ls[F + tf * 4 + 0], q.x);
    atomicAdd(&ls[F + tf * 4 + 1], q.y);
    atomicAdd(&ls[F + tf * 4 + 2], q.z);
    atomicAdd(&ls[F + tf * 4 + 3], q.w);
    __syncthreads();
    if (threadIdx.x < 2 * F) atomicAdd(&sums[threadIdx.x], ls[threadIdx.x]);
}

__global__ void bn_norm(float* __restrict__ y, const float* __restrict__ sums,
                        const float* __restrict__ gamma, const float* __restrict__ beta, int n,
                        int F, int relu) {
    int idx = blockIdx.x * blockDim.x + threadIdx.x;
    if (idx >= n * F) return;
    int f = idx % F;
    float mu = sums[f] / (float)n;
    float var = sums[F + f] / (float)n - mu * mu;
    float v = (y[idx] - mu) * rsqrtf(var + BN_EPS) * gamma[f] + beta[f];
    if (relu) v = fmaxf(v, 0.f);
    y[idx] = v;
}

extern "C" void kernel_launch(void* const* d_in, const int* in_sizes, int n_in, void* d_out,
                              int out_size, void* d_ws, size_t ws_size, hipStream_t stream) {
    const int N = NNODES, E = NEDGES;
    const float* x = (const float*)d_in[0];
    const int* ei = (const int*)d_in[1];
    const int* src = ei;
    const int* dst = ei + E;
    const float* W1 = (const float*)d_in[2];
    const float* as1 = (const float*)d_in[3];
    const float* ad1 = (const float*)d_in[4];
    const float* b1 = (const float*)d_in[5];
    const float* g1 = (const float*)d_in[6];
    const float* be1 = (const float*)d_in[7];
    const float* W2 = (const float*)d_in[8];
    const float* as2 = (const float*)d_in[9];
    const float* ad2 = (const float*)d_in[10];
    const float* b2 = (const float*)d_in[11];
    const float* g2 = (const float*)d_in[12];
    const float* be2 = (const float*)d_in[13];
    const float* W3 = (const float*)d_in[14];
    const float* as3 = (const float*)d_in[15];
    const float* ad3 = (const float*)d_in[16];
    const float* b3 = (const float*)d_in[17];
    const float* W4 = (const float*)d_in[18];
    const float* as4 = (const float*)d_in[19];
    const float* ad4 = (const float*)d_in[20];
    const float* b4 = (const float*)d_in[21];
    const float* g4 = (const float*)d_in[22];
    const float* be4 = (const float*)d_in[23];
    const float* W5 = (const float*)d_in[24];
    const float* as5 = (const float*)d_in[25];
    const float* ad5 = (const float*)d_in[26];
    const float* b5 = (const float*)d_in[27];
    float* out = (float*)d_out;

    // workspace layout
    float* ws = (float*)d_ws;
    float* bufA = ws;                          // N*128 (matmul out)
    float* bufB = ws + (size_t)N * 128;        // N*128 (layer activation)
    float* es = ws + (size_t)2 * N * 128;      // N*4
    float* ed = es + (size_t)N * 4;            // N*4
    float* sums = ed + (size_t)N * 4;          // 256
    int* cnt = (int*)(sums + 256);             // N
    int* off = cnt + N;                        // N+1
    int* cur = off + N + 1;                    // N
    int* ssorted = cur + N;                    // E+N

    const int TB = 256;
    const int gE = (E + TB - 1) / TB;
    const int gN = (N + TB - 1) / TB;
    const int gNF128 = (N * 128 + TB - 1) / TB;
    const int gNF32 = (N * 32 + TB - 1) / TB;
    const int gAgg = N / 4;
    const dim3 mmGrid128((N + 63) / 64, 2);
    const dim3 mmGrid32((N + 63) / 64, 1);

    // ---- one-time CSR-by-dst build ----
    deg_init<<<gN, TB, 0, stream>>>(cnt);
    hist_dst<<<gE, TB, 0, stream>>>(dst, cnt);
    scan50k<<<1, 1024, 0, stream>>>(cnt, off);
    hipMemsetAsync(cur, 0, (size_t)N * sizeof(int), stream);
    scatter_edges<<<gE, TB, 0, stream>>>(src, dst, off, cur, ssorted);
    self_loops<<<gN, TB, 0, stream>>>(off, ssorted);

    // ================= GAT1: 128 -> 4x32, relu, bn =================
    matmul_rt<64><<<mmGrid128, TB, 0, stream>>>(x, W1, bufA, N, 128, 128);
    attn_scores<4, 32><<<(N * 4 + TB - 1) / TB, TB, 0, stream>>>(bufA, as1, ad1, es, ed);
    node_agg<4, 32><<<gAgg, TB, 0, stream>>>(off, ssorted, bufA, es, ed, b1, bufB, 1);
    hipMemsetAsync(sums, 0, 256 * sizeof(float), stream);
    bn_stats<128><<<625, TB, 0, stream>>>(bufB, sums, N);
    bn_norm<<<gNF128, TB, 0, stream>>>(bufB, sums, g1, be1, N, 128, 0);

    // ================= GAT2: 128 -> 4x32, relu, bn =================
    matmul_rt<64><<<mmGrid128, TB, 0, stream>>>(bufB, W2, bufA, N, 128, 128);
    attn_scores<4, 32><<<(N * 4 + TB - 1) / TB, TB, 0, stream>>>(bufA, as2, ad2, es, ed);
    node_agg<4, 32><<<gAgg, TB, 0, stream>>>(off, ssorted, bufA, es, ed, b2, bufB, 1);
    hipMemsetAsync(sums, 0, 256 * sizeof(float), stream);
    bn_stats<128><<<625, TB, 0, stream>>>(bufB, sums, N);
    bn_norm<<<gNF128, TB, 0, stream>>>(bufB, sums, g2, be2, N, 128, 0);

    // ================= GAT3: 128 -> 32, relu =================
    matmul_rt<32><<<mmGrid32, TB, 0, stream>>>(bufB, W3, bufA, N, 128, 32);
    attn_scores<1, 32><<<gN, TB, 0, stream>>>(bufA, as3, ad3, es, ed);
    node_agg<1, 32><<<gAgg, TB, 0, stream>>>(off, ssorted, bufA, es, ed, b3, bufB, 1);

    // ================= GAT4: 32 -> 32, relu, bn, relu =================
    matmul_rt<32><<<mmGrid32, TB, 0, stream>>>(bufB, W4, bufA, N, 32, 32);
    attn_scores<1, 32><<<gN, TB, 0, stream>>>(bufA, as4, ad4, es, ed);
    node_agg<1, 32><<<gAgg, TB, 0, stream>>>(off, ssorted, bufA, es, ed, b4, bufB, 1);
    hipMemsetAsync(sums, 0, 256 * sizeof(float), stream);
    bn_stats<32><<<625, TB, 0, stream>>>(bufB, sums, N);
    bn_norm<<<gNF32, TB, 0, stream>>>(bufB, sums, g4, be4, N, 32, 1);

    // ================= GAT5: 32 -> 128, no act =================
    matmul_rt<64><<<mmGrid128, TB, 0, stream>>>(bufB, W5, bufA, N, 32, 128);
    attn_scores<1, 128><<<gN, TB, 0, stream>>>(bufA, as5, ad5, es, ed);
    node_agg<1, 128><<<gAgg, TB, 0, stream>>>(off, ssorted, bufA, es, ed, b5, out, 0);
}

// Round 5
// 742.589 us; speedup vs baseline: 2.9727x; 1.0614x over previous
//
#include <hip/hip_runtime.h>
#include <math.h>

#define NNODES 50000
#define NEDGES 800000
#define BN_EPS 1e-5f
#define DEGC 128   // LDS-cached in-edges per node; fallback path beyond

typedef unsigned int uint;
typedef unsigned short ushort;

// fp32 -> bf16 (RNE)
static __device__ __forceinline__ ushort f2bf(float f) {
    uint u = __float_as_uint(f);
    return (ushort)((u + 0x7fffu + ((u >> 16) & 1u)) >> 16);
}
// 2 packed bf16 -> 2 fp32 (elem0 = low 16 bits)
static __device__ __forceinline__ float2 bf2f(uint v) {
    float2 r;
    r.x = __uint_as_float(v << 16);
    r.y = __uint_as_float(v & 0xffff0000u);
    return r;
}

// ================= counting sort by dst =================
__global__ void deg_init(int* __restrict__ cnt) {
    int i = blockIdx.x * blockDim.x + threadIdx.x;
    if (i < NNODES) cnt[i] = 1;  // self-loop
}

__global__ void hist_dst(const int* __restrict__ dst, int* __restrict__ cnt) {
    int e = blockIdx.x * blockDim.x + threadIdx.x;
    if (e < NEDGES) atomicAdd(&cnt[dst[e]], 1);
}

__global__ void scan50k(const int* __restrict__ cnt, int* __restrict__ off) {
    __shared__ int wsum[16];
    int lane = threadIdx.x & 63, wid = threadIdx.x >> 6;
    int carry = 0;
    for (int base = 0; base < NNODES; base += 1024) {
        int i = base + threadIdx.x;
        int v = (i < NNODES) ? cnt[i] : 0;
        int x = v;
#pragma unroll
        for (int s = 1; s < 64; s <<= 1) {
            int t = __shfl_up(x, s);
            if (lane >= s) x += t;
        }
        if (lane == 63) wsum[wid] = x;
        __syncthreads();
        if (wid == 0) {
            int w = (lane < 16) ? wsum[lane] : 0;
#pragma unroll
            for (int s = 1; s < 16; s <<= 1) {
                int t = __shfl_up(w, s);
                if (lane >= s) w += t;
            }
            if (lane < 16) wsum[lane] = w;
        }
        __syncthreads();
        int woff = (wid > 0) ? wsum[wid - 1] : 0;
        int incl = x + woff;
        if (i < NNODES) off[i] = carry + incl - v;
        int tot = wsum[15];
        __syncthreads();
        carry += tot;
    }
    if (threadIdx.x == 0) off[NNODES] = carry;
}

__global__ void scatter_edges(const int* __restrict__ src, const int* __restrict__ dst,
                              const int* __restrict__ off, int* __restrict__ cur,
                              int* __restrict__ ssorted) {
    int e = blockIdx.x * blockDim.x + threadIdx.x;
    if (e < NEDGES) {
        int d = dst[e];
        int p = off[d] + atomicAdd(&cur[d], 1);
        ssorted[p] = src[e];
    }
}

__global__ void self_loops(const int* __restrict__ off, int* __restrict__ ssorted) {
    int d = blockIdx.x * blockDim.x + threadIdx.x;
    if (d < NNODES) ssorted[off[d + 1] - 1] = d;
}

// ===== dense matmul: Of[N,F](fp32) = X @ W; optionally also Obf (bf16 copy) =====
template <int BN, bool WBF>
__global__ __launch_bounds__(256) void matmul_rt(const float* __restrict__ X,
                                                 const float* __restrict__ W,
                                                 float* __restrict__ Of,
                                                 ushort* __restrict__ Obf, int N, int K, int F) {
    constexpr int TN = BN / 16;
    __shared__ float sX[16][64 + 4];
    __shared__ float sW[16][BN + 4];
    int tid = threadIdx.x;
    int rowBase = blockIdx.x * 64, colBase = blockIdx.y * BN;
    int tr = (tid >> 4) * 4, tc = (tid & 15) * TN;
    float acc[4][TN];
#pragma unroll
    for (int x = 0; x < 4; ++x)
#pragma unroll
        for (int y = 0; y < TN; ++y) acc[x][y] = 0.f;

    for (int k0 = 0; k0 < K; k0 += 16) {
        for (int i = tid; i < 64 * 16; i += 256) {
            int r = i >> 4, k = i & 15;
            int gr = rowBase + r;
            sX[k][r] = (gr < N) ? X[(size_t)gr * K + k0 + k] : 0.f;
        }
        for (int i = tid; i < 16 * BN; i += 256) {
            int k = i / BN, c = i % BN;
            sW[k][c] = W[(size_t)(k0 + k) * F + colBase + c];
        }
        __syncthreads();
#pragma unroll
        for (int k = 0; k < 16; ++k) {
            float4 av = *(const float4*)&sX[k][tr];
            float a[4] = {av.x, av.y, av.z, av.w};
            float b[TN];
            if constexpr (TN == 4) {
                float4 bv = *(const float4*)&sW[k][tc];
                b[0] = bv.x; b[1] = bv.y; b[2] = bv.z; b[3] = bv.w;
            } else {
                float2 bv = *(const float2*)&sW[k][tc];
                b[0] = bv.x; b[1] = bv.y;
            }
#pragma unroll
            for (int x = 0; x < 4; ++x)
#pragma unroll
                for (int y = 0; y < TN; ++y) acc[x][y] += a[x] * b[y];
        }
        __syncthreads();
    }
#pragma unroll
    for (int x = 0; x < 4; ++x) {
        int gr = rowBase + tr + x;
        if (gr < N) {
#pragma unroll
            for (int y = 0; y < TN; ++y) Of[(size_t)gr * F + colBase + tc + y] = acc[x][y];
            if constexpr (WBF) {
#pragma unroll
                for (int y = 0; y < TN; y += 2) {
                    uint pk = (uint)f2bf(acc[x][y]) | ((uint)f2bf(acc[x][y + 1]) << 16);
                    *(uint*)(Obf + (size_t)gr * F + colBase + tc + y) = pk;
                }
            }
        }
    }
}

// ================= per-node attention scores (fp32 h — exact logits) =================
template <int HH, int DD>
__global__ void attn_scores(const float* __restrict__ Hb, const float* __restrict__ asrc,
                            const float* __restrict__ adst, float* __restrict__ es,
                            float* __restrict__ ed) {
    int idx = blockIdx.x * blockDim.x + threadIdx.x;
    if (idx >= NNODES * HH) return;
    int h = idx % HH;
    const float4* hp = (const float4*)(Hb + (size_t)idx * DD);
    const float4* ap = (const float4*)(asrc + h * DD);
    const float4* bp = (const float4*)(adst + h * DD);
    float s = 0.f, t = 0.f;
#pragma unroll
    for (int q = 0; q < DD / 4; ++q) {
        float4 v = hp[q], a = ap[q], b = bp[q];
        s += v.x * a.x + v.y * a.y + v.z * a.z + v.w * a.w;
        t += v.x * b.x + v.y * b.y + v.z * b.z + v.w * b.w;
    }
    es[idx] = s;
    ed[idx] = t;
}

// ====== gather softmax-aggregate, F=128, h in bf16 (one wave per dst node) ======
template <int HH>
__global__ __launch_bounds__(256) void node_agg_bf(const int* __restrict__ off,
                                                   const int* __restrict__ ssorted,
                                                   const ushort* __restrict__ Hb,
                                                   const float* __restrict__ es,
                                                   const float* __restrict__ ed,
                                                   const float* __restrict__ bias,
                                                   float* __restrict__ outp, int relu) {
    __shared__ float lds_ex[4][DEGC * HH];
    __shared__ int lds_s[4][DEGC];
    int wib = threadIdx.x >> 6;
    int lane = threadIdx.x & 63;
    int d = blockIdx.x * 4 + wib;
    int beg = off[d], end = off[d + 1];
    int m = end - beg;  // >= 1

    float edv[HH];
#pragma unroll
    for (int h = 0; h < HH; ++h) edv[h] = ed[(size_t)d * HH + h];
    float denp[HH];
#pragma unroll
    for (int h = 0; h < HH; ++h) denp[h] = 0.f;

    for (int base = 0; base < m; base += 64) {
        int i = base + lane;
        if (i < m) {
            int s = ssorted[beg + i];
            if (i < DEGC) lds_s[wib][i] = s;
#pragma unroll
            for (int h = 0; h < HH; ++h) {
                float a = es[(size_t)s * HH + h] + edv[h];
                a = a > 0.f ? a : 0.2f * a;
                float ex = __expf(a);
                denp[h] += ex;
                if (i < DEGC) lds_ex[wib][i * HH + h] = ex;
            }
        }
    }
#pragma unroll
    for (int h = 0; h < HH; ++h)
#pragma unroll
        for (int sft = 1; sft < 64; sft <<= 1) denp[h] += __shfl_xor(denp[h], sft);

    __syncthreads();

    const uint* Hu = (const uint*)Hb;
    // lane owns features 2*lane, 2*lane+1; head = lane>>4 (HH=4) or 0
    int head;
    float den, edl;
    if constexpr (HH == 4) {
        head = lane >> 4;
        den = (lane < 32) ? ((lane < 16) ? denp[0] : denp[1])
                          : ((lane < 48) ? denp[2] : denp[3]);
        edl = (lane < 32) ? ((lane < 16) ? edv[0] : edv[1])
                          : ((lane < 48) ? edv[2] : edv[3]);
    } else {
        head = 0;
        den = denp[0];
        edl = edv[0];
    }
    float inv = 1.f / den;
    float acc0 = 0.f, acc1 = 0.f;
    for (int i = 0; i < m; ++i) {
        int s;
        float ex;
        if (i < DEGC) {
            s = lds_s[wib][i];
            ex = lds_ex[wib][i * HH + head];
        } else {
            s = ssorted[beg + i];
            float a = es[(size_t)s * HH + head] + edl;
            a = a > 0.f ? a : 0.2f * a;
            ex = __expf(a);
        }
        uint v = Hu[(size_t)s * 64 + lane];
        float2 f = bf2f(v);
        float w = ex * inv;
        acc0 += w * f.x;
        acc1 += w * f.y;
    }
    float v0 = acc0 + bias[2 * lane];
    float v1 = acc1 + bias[2 * lane + 1];
    if (relu) { v0 = fmaxf(v0, 0.f); v1 = fmaxf(v1, 0.f); }
    *(float2*)(outp + (size_t)d * 128 + 2 * lane) = make_float2(v0, v1);
}

// ====== gather softmax-aggregate, F=32, HH=1, h in fp32 (one wave per dst node) ======
__global__ __launch_bounds__(256) void node_agg_f32(const int* __restrict__ off,
                                                    const int* __restrict__ ssorted,
                                                    const float* __restrict__ Hb,
                                                    const float* __restrict__ es,
                                                    const float* __restrict__ ed,
                                                    const float* __restrict__ bias,
                                                    float* __restrict__ outp, int relu) {
    __shared__ float lds_ex[4][DEGC];
    __shared__ int lds_s[4][DEGC];
    int wib = threadIdx.x >> 6;
    int lane = threadIdx.x & 63;
    int d = blockIdx.x * 4 + wib;
    int beg = off[d], end = off[d + 1];
    int m = end - beg;

    float edv = ed[d];
    float denp = 0.f;
    for (int base = 0; base < m; base += 64) {
        int i = base + lane;
        if (i < m) {
            int s = ssorted[beg + i];
            if (i < DEGC) lds_s[wib][i] = s;
            float a = es[s] + edv;
            a = a > 0.f ? a : 0.2f * a;
            float ex = __expf(a);
            denp += ex;
            if (i < DEGC) lds_ex[wib][i] = ex;
        }
    }
#pragma unroll
    for (int sft = 1; sft < 64; sft <<= 1) denp += __shfl_xor(denp, sft);

    __syncthreads();

    int sub = lane >> 5, f = lane & 31;
    float inv = 1.f / denp;
    float acc = 0.f;
    for (int i = sub; i < m; i += 2) {
        int s;
        float ex;
        if (i < DEGC) {
            s = lds_s[wib][i];
            ex = lds_ex[wib][i];
        } else {
            s = ssorted[beg + i];
            float a = es[s] + edv;
            a = a > 0.f ? a : 0.2f * a;
            ex = __expf(a);
        }
        acc += ex * inv * Hb[(size_t)s * 32 + f];
    }
    acc += __shfl_xor(acc, 32);
    if (sub == 0) {
        float v = acc + bias[f];
        if (relu) v = fmaxf(v, 0.f);
        outp[(size_t)d * 32 + f] = v;
    }
}

// ================= batchnorm =================
template <int F>
__global__ __launch_bounds__(256) void bn_stats(const float* __restrict__ x,
                                                float* __restrict__ sums, int n) {
    constexpr int TPR = F / 4;
    constexpr int RPB = 256 / TPR;
    __shared__ float ls[2 * F];
    if (threadIdx.x < 2 * F) ls[threadIdx.x] = 0.f;
    int tf = threadIdx.x % TPR;
    int tr = threadIdx.x / TPR;
    float4 s = make_float4(0.f, 0.f, 0.f, 0.f), q = make_float4(0.f, 0.f, 0.f, 0.f);
    for (int r = blockIdx.x * RPB + tr; r < n; r += gridDim.x * RPB) {
        float4 v = *(const float4*)(x + (size_t)r * F + tf * 4);
        s.x += v.x; s.y += v.y; s.z += v.z; s.w += v.w;
        q.x += v.x * v.x; q.y += v.y * v.y; q.z += v.z * v.z; q.w += v.w * v.w;
    }
    __syncthreads();
    atomicAdd(&ls[tf * 4 + 0], s.x);
    atomicAdd(&ls[tf * 4 + 1], s.y);
    atomicAdd(&ls[tf * 4 + 2], s.z);
    atomicAdd(&ls[tf * 4 + 3], s.w);
    atomicAdd(&ls[F + tf * 4 + 0], q.x);
    atomicAdd(&ls[F + tf * 4 + 1], q.y);
    atomicAdd(&ls[F + tf * 4 + 2], q.z);
    atomicAdd(&ls[F + tf * 4 + 3], q.w);
    __syncthreads();
    if (threadIdx.x < 2 * F) atomicAdd(&sums[threadIdx.x], ls[threadIdx.x]);
}

__global__ void bn_norm(float* __restrict__ y, const float* __restrict__ sums,
                        const float* __restrict__ gamma, const float* __restrict__ beta, int n,
                        int F, int relu) {
    int idx = blockIdx.x * blockDim.x + threadIdx.x;
    if (idx >= n * F) return;
    int f = idx % F;
    float mu = sums[f] / (float)n;
    float var = sums[F + f] / (float)n - mu * mu;
    float v = (y[idx] - mu) * rsqrtf(var + BN_EPS) * gamma[f] + beta[f];
    if (relu) v = fmaxf(v, 0.f);
    y[idx] = v;
}

extern "C" void kernel_launch(void* const* d_in, const int* in_sizes, int n_in, void* d_out,
                              int out_size, void* d_ws, size_t ws_size, hipStream_t stream) {
    const int N = NNODES, E = NEDGES;
    const float* x = (const float*)d_in[0];
    const int* ei = (const int*)d_in[1];
    const int* src = ei;
    const int* dst = ei + E;
    const float* W1 = (const float*)d_in[2];
    const float* as1 = (const float*)d_in[3];
    const float* ad1 = (const float*)d_in[4];
    const float* b1 = (const float*)d_in[5];
    const float* g1 = (const float*)d_in[6];
    const float* be1 = (const float*)d_in[7];
    const float* W2 = (const float*)d_in[8];
    const float* as2 = (const float*)d_in[9];
    const float* ad2 = (const float*)d_in[10];
    const float* b2 = (const float*)d_in[11];
    const float* g2 = (const float*)d_in[12];
    const float* be2 = (const float*)d_in[13];
    const float* W3 = (const float*)d_in[14];
    const float* as3 = (const float*)d_in[15];
    const float* ad3 = (const float*)d_in[16];
    const float* b3 = (const float*)d_in[17];
    const float* W4 = (const float*)d_in[18];
    const float* as4 = (const float*)d_in[19];
    const float* ad4 = (const float*)d_in[20];
    const float* b4 = (const float*)d_in[21];
    const float* g4 = (const float*)d_in[22];
    const float* be4 = (const float*)d_in[23];
    const float* W5 = (const float*)d_in[24];
    const float* as5 = (const float*)d_in[25];
    const float* ad5 = (const float*)d_in[26];
    const float* b5 = (const float*)d_in[27];
    float* out = (float*)d_out;

    // workspace layout (float-sized slots)
    float* ws = (float*)d_ws;
    float* bufAf = ws;                          // N*128 fp32 (matmul out h, exact)
    float* bufB = ws + (size_t)N * 128;         // N*128 fp32 (layer activation)
    ushort* bufAbf = (ushort*)(ws + (size_t)2 * N * 128);  // N*128 bf16 = N*64 floats
    float* es = ws + (size_t)2 * N * 128 + (size_t)N * 64;  // N*4
    float* ed = es + (size_t)N * 4;             // N*4
    float* sums = ed + (size_t)N * 4;           // 256
    int* cnt = (int*)(sums + 256);              // N
    int* off = cnt + N;                         // N+1
    int* cur = off + N + 1;                     // N
    int* ssorted = cur + N;                     // E+N

    const int TB = 256;
    const int gE = (E + TB - 1) / TB;
    const int gN = (N + TB - 1) / TB;
    const int gNF128 = (N * 128 + TB - 1) / TB;
    const int gNF32 = (N * 32 + TB - 1) / TB;
    const int gAgg = N / 4;
    const dim3 mmGrid128((N + 63) / 64, 2);
    const dim3 mmGrid32((N + 63) / 64, 1);

    // ---- one-time CSR-by-dst build ----
    deg_init<<<gN, TB, 0, stream>>>(cnt);
    hist_dst<<<gE, TB, 0, stream>>>(dst, cnt);
    scan50k<<<1, 1024, 0, stream>>>(cnt, off);
    hipMemsetAsync(cur, 0, (size_t)N * sizeof(int), stream);
    scatter_edges<<<gE, TB, 0, stream>>>(src, dst, off, cur, ssorted);
    self_loops<<<gN, TB, 0, stream>>>(off, ssorted);

    // ================= GAT1: 128 -> 4x32, relu, bn =================
    matmul_rt<64, true><<<mmGrid128, TB, 0, stream>>>(x, W1, bufAf, bufAbf, N, 128, 128);
    attn_scores<4, 32><<<(N * 4 + TB - 1) / TB, TB, 0, stream>>>(bufAf, as1, ad1, es, ed);
    node_agg_bf<4><<<gAgg, TB, 0, stream>>>(off, ssorted, bufAbf, es, ed, b1, bufB, 1);
    hipMemsetAsync(sums, 0, 256 * sizeof(float), stream);
    bn_stats<128><<<625, TB, 0, stream>>>(bufB, sums, N);
    bn_norm<<<gNF128, TB, 0, stream>>>(bufB, sums, g1, be1, N, 128, 0);

    // ================= GAT2: 128 -> 4x32, relu, bn =================
    matmul_rt<64, true><<<mmGrid128, TB, 0, stream>>>(bufB, W2, bufAf, bufAbf, N, 128, 128);
    attn_scores<4, 32><<<(N * 4 + TB - 1) / TB, TB, 0, stream>>>(bufAf, as2, ad2, es, ed);
    node_agg_bf<4><<<gAgg, TB, 0, stream>>>(off, ssorted, bufAbf, es, ed, b2, bufB, 1);
    hipMemsetAsync(sums, 0, 256 * sizeof(float), stream);
    bn_stats<128><<<625, TB, 0, stream>>>(bufB, sums, N);
    bn_norm<<<gNF128, TB, 0, stream>>>(bufB, sums, g2, be2, N, 128, 0);

    // ================= GAT3: 128 -> 32, relu (fp32 path) =================
    matmul_rt<32, false><<<mmGrid32, TB, 0, stream>>>(bufB, W3, bufAf, nullptr, N, 128, 32);
    attn_scores<1, 32><<<gN, TB, 0, stream>>>(bufAf, as3, ad3, es, ed);
    node_agg_f32<<<gAgg, TB, 0, stream>>>(off, ssorted, bufAf, es, ed, b3, bufB, 1);

    // ================= GAT4: 32 -> 32, relu, bn, relu (fp32 path) =================
    matmul_rt<32, false><<<mmGrid32, TB, 0, stream>>>(bufB, W4, bufAf, nullptr, N, 32, 32);
    attn_scores<1, 32><<<gN, TB, 0, stream>>>(bufAf, as4, ad4, es, ed);
    node_agg_f32<<<gAgg, TB, 0, stream>>>(off, ssorted, bufAf, es, ed, b4, bufB, 1);
    hipMemsetAsync(sums, 0, 256 * sizeof(float), stream);
    bn_stats<32><<<625, TB, 0, stream>>>(bufB, sums, N);
    bn_norm<<<gNF32, TB, 0, stream>>>(bufB, sums, g4, be4, N, 32, 1);

    // ================= GAT5: 32 -> 128, no act =================
    matmul_rt<64, true><<<mmGrid128, TB, 0, stream>>>(bufB, W5, bufAf, bufAbf, N, 32, 128);
    attn_scores<1, 128><<<gN, TB, 0, stream>>>(bufAf, as5, ad5, es, ed);
    node_agg_bf<1><<<gAgg, TB, 0, stream>>>(off, ssorted, bufAbf, es, ed, b5, out, 0);
}